// Round 2
// baseline (1511.608 us; speedup 1.0000x reference)
//
#include <hip/hip_runtime.h>
#include <hip/hip_bf16.h>
#include <hip/hip_fp16.h>

typedef unsigned int u32;
typedef unsigned short u16;
typedef __bf16 bf16x8 __attribute__((ext_vector_type(8)));
typedef float floatx4 __attribute__((ext_vector_type(4)));

#define SCALE 0.08838834764831845f
#define FETCH_MAX 204

__device__ __forceinline__ float bf2f(u16 u) {
    union { u32 i; float f; } v; v.i = ((u32)u) << 16; return v.f;
}
__device__ __forceinline__ u16 f2bf(float f) {
    union { float f; u32 i; } v; v.f = f;
    u32 r = v.i + 0x7FFFu + ((v.i >> 16) & 1u);
    return (u16)(r >> 16);
}
__device__ __forceinline__ u16 f2h_bits(float f) {
    __half h = __float2half(f);
    union { __half h; u16 u; } v; v.h = h; return v.u;
}
__device__ __forceinline__ float h_bits2f(u16 u) {
    union { __half h; u16 u; } v; v.u = u; return __half2float(v.h);
}

// ---------------------------------------------------------------- detect input dtype
__global__ void detect_k(const u32* cosw, int* flag) {
    if (threadIdx.x == 0 && blockIdx.x == 0)
        *flag = (cosw[0] == 0x3F800000u) ? 1 : 0;   // 1 = inputs are fp32
}

__global__ __launch_bounds__(256) void zero_k(int* p, int n) {
    int i = blockIdx.x * 256 + threadIdx.x;
    if (i < n) p[i] = 0;
}

// ---------------------------------------------------------------- convert (fp32 -> bf16), only when flag==1
__global__ __launch_bounds__(256) void convert_k(
    const int* flagp, const float* hs, const float* wq, const float* wk,
    const float* wv, const float* wo,
    u16* chs, u16* cwq, u16* cwk, u16* cwv, u16* cwo)
{
    if (*flagp == 0) return;
    const long S0 = 4194304/4, S1 = 16777216/4, S2 = 4194304/4, S3 = 4194304/4, S4 = 16777216/4;
    const long total = S0+S1+S2+S3+S4;
    for (long idx = (long)blockIdx.x*256 + threadIdx.x; idx < total; idx += (long)gridDim.x*256) {
        const float* src; u16* dst; long o = idx;
        if (o < S0)            { src = hs; dst = chs; }
        else if ((o -= S0) < S1) { src = wq; dst = cwq; }
        else if ((o -= S1) < S2) { src = wk; dst = cwk; }
        else if ((o -= S2) < S3) { src = wv; dst = cwv; }
        else                   { o -= S3; src = wo; dst = cwo; }
        float4 v = ((const float4*)src)[o];
        u32 lo = (u32)f2bf(v.x) | ((u32)f2bf(v.y) << 16);
        u32 hi = (u32)f2bf(v.z) | ((u32)f2bf(v.w) << 16);
        ((uint2*)dst)[o] = make_uint2(lo, hi);
    }
}

// ---------------------------------------------------------------- GEMM  C[M,N] = A[M,K] * B[N,K]^T
__global__ __launch_bounds__(256) void gemm_bt(
    const int* flagp,
    const u16* A0, const u16* A1,
    const u16* B0a, const u16* B0b,
    const u16* B1a, const u16* B1b,
    const u16* B2a, const u16* B2b,
    int n0, int n1,
    u16* Cb, float* Cf,
    int M, int N, int K, int ldc)
{
    const int flag = *flagp;
    const u16* A  = flag ? A1 : A0;
    const u16* Bq = flag ? B0b : B0a;
    const u16* Bk = flag ? B1b : B1a;
    const u16* Bv = flag ? B2b : B2a;
    __shared__ u16 Al[128][72];   // +8 pad: conflict-free b128 frag reads
    __shared__ u16 Bl[128][72];
    const int tid = threadIdx.x;
    const int wave = tid >> 6, lane = tid & 63;
    const int qd = lane >> 4, l16 = lane & 15;
    const int wm = wave & 1, wn = wave >> 1;
    const int m0 = blockIdx.y * 128, nb = blockIdx.x * 128;
    floatx4 acc[4][4];
    floatx4 zf = {0.f, 0.f, 0.f, 0.f};
    for (int mt = 0; mt < 4; ++mt) for (int nt = 0; nt < 4; ++nt) acc[mt][nt] = zf;

    for (int k0 = 0; k0 < K; k0 += 64) {
        #pragma unroll
        for (int it = 0; it < 4; ++it) {
            int idx = tid + it*256;
            int r = idx >> 3, c8 = idx & 7;
            uint4 va = *(const uint4*)&A[(size_t)(m0 + r)*K + k0 + c8*8];
            *(uint4*)&Al[r][c8*8] = va;
            int f = nb + r;
            const u16* Brow = (f < n0) ? (Bq + (size_t)f*K)
                             : (f < n0 + n1) ? (Bk + (size_t)(f - n0)*K)
                             : (Bv + (size_t)(f - n0 - n1)*K);
            uint4 vb = *(const uint4*)&Brow[k0 + c8*8];
            *(uint4*)&Bl[r][c8*8] = vb;
        }
        __syncthreads();
        #pragma unroll
        for (int ks = 0; ks < 2; ++ks) {
            bf16x8 af[4], bfr[4];
            #pragma unroll
            for (int mt = 0; mt < 4; ++mt)
                af[mt] = *(const bf16x8*)&Al[wm*64 + mt*16 + l16][ks*32 + qd*8];
            #pragma unroll
            for (int nt = 0; nt < 4; ++nt)
                bfr[nt] = *(const bf16x8*)&Bl[wn*64 + nt*16 + l16][ks*32 + qd*8];
            #pragma unroll
            for (int mt = 0; mt < 4; ++mt)
                #pragma unroll
                for (int nt = 0; nt < 4; ++nt)
                    acc[mt][nt] = __builtin_amdgcn_mfma_f32_16x16x32_bf16(af[mt], bfr[nt], acc[mt][nt], 0, 0, 0);
        }
        __syncthreads();
    }
    const bool of32 = (Cf != nullptr) && flag;
    #pragma unroll
    for (int mt = 0; mt < 4; ++mt)
        #pragma unroll
        for (int nt = 0; nt < 4; ++nt)
            #pragma unroll
            for (int rg = 0; rg < 4; ++rg) {
                int row = m0 + wm*64 + mt*16 + qd*4 + rg;   // C: row=(lane>>4)*4+reg
                int col = nb + wn*64 + nt*16 + l16;         //    col=lane&15
                float v = acc[mt][nt][rg];
                if (of32) Cf[(size_t)row*ldc + col] = v;
                else      Cb[(size_t)row*ldc + col] = f2bf(v);
            }
}

// ---------------------------------------------------------------- RoPE in-place on Q (slots 0..31) and K (32..39)
__global__ __launch_bounds__(256) void rope_k(const int* flagp, u16* QKV,
                                              const void* cosp, const void* sinp)
{
    const int flag = *flagp;
    long idx = (long)blockIdx.x*256 + threadIdx.x;   // 1024*40*64
    int d = (int)(idx & 63);
    int t = (int)(idx >> 6);
    int slot = t % 40, i = t / 40;
    int col0 = (slot < 32) ? slot*128 : 4096 + (slot - 32)*128;
    size_t base = (size_t)i*6144 + col0;
    float q1 = bf2f(QKV[base + d]), q2 = bf2f(QKV[base + d + 64]);
    float c, s;
    if (flag) { c = ((const float*)cosp)[i*128 + d]; s = ((const float*)sinp)[i*128 + d]; }
    else      { c = bf2f(((const u16*)cosp)[i*128 + d]); s = bf2f(((const u16*)sinp)[i*128 + d]); }
    QKV[base + d]      = f2bf(q1*c - q2*s);
    QKV[base + d + 64] = f2bf(q2*c + q1*s);
}

// ---------------------------------------------------------------- head-0 causal row max (scaled)
__global__ __launch_bounds__(256) void rowmax0_k(const u16* QKV, float* rowmax0)
{
    const int i = blockIdx.x;
    __shared__ float Qs[128];
    __shared__ float wm4[4];
    const int tid = threadIdx.x, wave = tid >> 6, lane = tid & 63;
    if (tid < 16) {
        uint4 v = *(const uint4*)&QKV[(size_t)i*6144 + tid*8];
        Qs[tid*8+0] = bf2f((u16)(v.x & 0xffff)); Qs[tid*8+1] = bf2f((u16)(v.x >> 16));
        Qs[tid*8+2] = bf2f((u16)(v.y & 0xffff)); Qs[tid*8+3] = bf2f((u16)(v.y >> 16));
        Qs[tid*8+4] = bf2f((u16)(v.z & 0xffff)); Qs[tid*8+5] = bf2f((u16)(v.z >> 16));
        Qs[tid*8+6] = bf2f((u16)(v.w & 0xffff)); Qs[tid*8+7] = bf2f((u16)(v.w >> 16));
    }
    __syncthreads();
    float mx = -3.0e38f;
    for (int j = tid; j <= i; j += 256) {
        const u16* Kr = &QKV[(size_t)j*6144 + 4096];   // kv head 0
        float acc = 0.f;
        #pragma unroll
        for (int c8 = 0; c8 < 16; ++c8) {
            uint4 v = *(const uint4*)&Kr[c8*8];
            acc += Qs[c8*8+0]*bf2f((u16)(v.x & 0xffff)) + Qs[c8*8+1]*bf2f((u16)(v.x >> 16));
            acc += Qs[c8*8+2]*bf2f((u16)(v.y & 0xffff)) + Qs[c8*8+3]*bf2f((u16)(v.y >> 16));
            acc += Qs[c8*8+4]*bf2f((u16)(v.z & 0xffff)) + Qs[c8*8+5]*bf2f((u16)(v.z >> 16));
            acc += Qs[c8*8+6]*bf2f((u16)(v.w & 0xffff)) + Qs[c8*8+7]*bf2f((u16)(v.w >> 16));
        }
        mx = fmaxf(mx, acc * SCALE);
    }
    #pragma unroll
    for (int off = 1; off < 64; off <<= 1) mx = fmaxf(mx, __shfl_xor(mx, off, 64));
    if (lane == 0) wm4[wave] = mx;
    __syncthreads();
    if (tid == 0) rowmax0[i] = fmaxf(fmaxf(wm4[0], wm4[1]), fmaxf(wm4[2], wm4[3]));
}

// ---------------------------------------------------------------- per-(head,row) count of s >= head0max - 5
__global__ __launch_bounds__(256) void qk_count(
    const u16* QKV, const float* rowmax0, int* count_sum)
{
    const int bid = blockIdx.x;
    const int h = bid >> 6, rb = bid & 63;
    const int r0 = rb * 16, g = h >> 2;
    __shared__ u16 Kl[128][72];
    __shared__ u16 Ql[16][136];
    __shared__ int redcnt[4][16];
    const int tid = threadIdx.x, wave = tid >> 6, lane = tid & 63;
    const int qd = lane >> 4, l16 = lane & 15;
    {
        int r = tid >> 4, c8 = tid & 15;
        uint4 v = *(const uint4*)&QKV[(size_t)(r0 + r)*6144 + h*128 + c8*8];
        *(uint4*)&Ql[r][c8*8] = v;
    }
    __syncthreads();
    bf16x8 af[4];
    #pragma unroll
    for (int ks = 0; ks < 4; ++ks) af[ks] = *(const bf16x8*)&Ql[l16][ks*32 + qd*8];
    float rm0[4]; int runcnt[4];
    #pragma unroll
    for (int rg = 0; rg < 4; ++rg) {
        runcnt[rg] = 0;
        rm0[rg] = rowmax0[r0 + qd*4 + rg] - 5.0f;
    }
    const int jtiles = (r0 + 16 + 127) >> 7;
    for (int ct = 0; ct < jtiles; ++ct) {
        __syncthreads();
        #pragma unroll
        for (int it = 0; it < 8; ++it) {
            int idx = tid + it*256;
            int r = idx >> 4, c8 = idx & 15;
            uint4 v = *(const uint4*)&QKV[(size_t)(ct*128 + r)*6144 + 4096 + g*128 + c8*8];
            *(uint4*)&Kl[r][c8*8] = v;
        }
        __syncthreads();
        const int jw = wave * 32;
        #pragma unroll
        for (int nt = 0; nt < 2; ++nt) {
            floatx4 sa = {0.f, 0.f, 0.f, 0.f};
            #pragma unroll
            for (int ks = 0; ks < 4; ++ks) {
                bf16x8 bfr = *(const bf16x8*)&Kl[jw + nt*16 + l16][ks*32 + qd*8];
                sa = __builtin_amdgcn_mfma_f32_16x16x32_bf16(af[ks], bfr, sa, 0, 0, 0);
            }
            const int jc = ct*128 + jw + nt*16 + l16;
            #pragma unroll
            for (int rg = 0; rg < 4; ++rg) {
                float s = sa[rg] * SCALE;
                int i = r0 + qd*4 + rg;
                if (jc <= i) runcnt[rg] += (s >= rm0[rg]) ? 1 : 0;
            }
        }
    }
    #pragma unroll
    for (int off = 1; off < 16; off <<= 1)
        #pragma unroll
        for (int rg = 0; rg < 4; ++rg)
            runcnt[rg] += __shfl_xor(runcnt[rg], off, 64);
    if (l16 == 0)
        for (int rg = 0; rg < 4; ++rg)
            redcnt[wave][qd*4 + rg] = runcnt[rg];
    __syncthreads();
    if (tid < 16) {
        int c = redcnt[0][tid] + redcnt[1][tid] + redcnt[2][tid] + redcnt[3][tid];
        atomicAdd(&count_sum[r0 + tid], c);
    }
}

// ---------------------------------------------------------------- fused: recompute scores -> exact top-k -> softmax -> PV
__global__ __launch_bounds__(256) void select_attn(
    const u16* QKV, const int* count_sum, u16* attn)
{
    const int bid = blockIdx.x;
    const int h = bid >> 6, rb = bid & 63;
    const int r0 = rb * 16, g = h >> 2;
    const int tid = threadIdx.x, wave = tid >> 6, lane = tid & 63;
    const int qd = lane >> 4, l16 = lane & 15;
    __shared__ u16 Ql[16][136];
    __shared__ u16 Kv[64][136];      // K tile in phase A, V tile in phase C
    __shared__ u16 SP[16][1032];     // fp16 scores, overwritten with bf16 probs
    __shared__ float denom[16];

    const int jtc = (r0 + 16 + 63) >> 6;   // number of 64-wide j tiles

    // stage Q (16 x 128)
    {
        int r = tid >> 4, c8 = tid & 15;
        uint4 v = *(const uint4*)&QKV[(size_t)(r0 + r)*6144 + h*128 + c8*8];
        *(uint4*)&Ql[r][c8*8] = v;
    }
    __syncthreads();
    bf16x8 af[4];
    #pragma unroll
    for (int ks = 0; ks < 4; ++ks) af[ks] = *(const bf16x8*)&Ql[l16][ks*32 + qd*8];

    // ---- phase A: scores (MFMA) -> SP as fp16
    for (int ct = 0; ct < jtc; ++ct) {
        __syncthreads();
        #pragma unroll
        for (int it = 0; it < 4; ++it) {
            int idx = tid + it*256;
            int r = idx >> 4, c8 = idx & 15;
            uint4 v = *(const uint4*)&QKV[(size_t)(ct*64 + r)*6144 + 4096 + g*128 + c8*8];
            *(uint4*)&Kv[r][c8*8] = v;
        }
        __syncthreads();
        floatx4 sa = {0.f, 0.f, 0.f, 0.f};
        #pragma unroll
        for (int ks = 0; ks < 4; ++ks) {
            bf16x8 bfr = *(const bf16x8*)&Kv[wave*16 + l16][ks*32 + qd*8];
            sa = __builtin_amdgcn_mfma_f32_16x16x32_bf16(af[ks], bfr, sa, 0, 0, 0);
        }
        #pragma unroll
        for (int rg = 0; rg < 4; ++rg)
            SP[qd*4 + rg][ct*64 + wave*16 + l16] = f2h_bits(sa[rg] * SCALE);
    }
    __syncthreads();

    // ---- phase B: per wave-row exact top-k (16-bit key bisection) + probs
    for (int batch = 0; batch < 4; ++batch) {
        const int m = batch*4 + wave;
        const int i = r0 + m, n = i + 1;
        const int nch = (n + 63) >> 6;
        float sv[16]; u16 key[16];
        #pragma unroll
        for (int c = 0; c < 16; ++c) { sv[c] = 0.f; key[c] = 0; }
        float rmax = -3.0e38f;
        for (int c = 0; c < nch; ++c) {
            int j = c*64 + lane;
            u16 hb = SP[m][j];
            float s = h_bits2f(hb);
            sv[c] = s;
            if (j < n) {
                key[c] = (u16)(hb ^ ((hb & 0x8000u) ? 0xFFFFu : 0x8000u));  // order-preserving
                rmax = fmaxf(rmax, s);
            }
        }
        #pragma unroll
        for (int off = 1; off < 64; off <<= 1) rmax = fmaxf(rmax, __shfl_xor(rmax, off, 64));

        const bool full = (i < FETCH_MAX);
        u32 Kstar = 0; int quota = 0;
        if (!full) {
            int k = count_sum[i] >> 5;              // floor(mean over 32 heads)
            if (k > FETCH_MAX) k = FETCH_MAX;
            if (k < 1) k = 1;
            // bisection: Kstar = max t with count(key >= t) >= k.
            // invalid lanes have key==0 and every valid key >= 1, so t>=1 excludes them.
            u32 t = 0;
            for (int bit = 15; bit >= 0; --bit) {
                u32 tc = t | (1u << bit);
                int cnt = 0;
                for (int c = 0; c < nch; ++c)
                    cnt += __popcll(__ballot((u32)key[c] >= tc));
                if (cnt >= k) t = tc;
            }
            Kstar = t;
            int cntgt = 0;
            for (int c = 0; c < nch; ++c)
                cntgt += __popcll(__ballot((u32)key[c] > Kstar));
            quota = k - cntgt;                      // kept among keys == Kstar (>=1)
        }
        // probs (unnormalized); ties at Kstar kept by ascending index (stable argsort)
        float psum = 0.f; int eqbase = 0;
        for (int c = 0; c < 16; ++c) {
            int j = c*64 + lane;
            bool valid = (c < nch) && (j < n);
            bool keep;
            if (full) keep = valid;
            else {
                bool eq = valid && ((u32)key[c] == Kstar);
                unsigned long long em = __ballot(eq);
                int rk = eqbase + __popcll(em & ((1ull << lane) - 1ull));
                keep = valid && (((u32)key[c] > Kstar) || (eq && rk < quota));
                eqbase += __popcll(em);
            }
            float p = keep ? __expf(sv[c] - rmax) : 0.f;
            psum += p;
            if (c < jtc) SP[m][j] = f2bf(p);        // overwrite scores with bf16 probs
        }
        #pragma unroll
        for (int off = 1; off < 64; off <<= 1) psum += __shfl_xor(psum, off, 64);
        if (lane == 0) denom[m] = psum;
    }
    __syncthreads();

    // ---- phase C: PV over all tiles
    floatx4 oacc[2];
    floatx4 zf = {0.f, 0.f, 0.f, 0.f};
    oacc[0] = zf; oacc[1] = zf;
    for (int jt = 0; jt < jtc; ++jt) {
        __syncthreads();
        #pragma unroll
        for (int it = 0; it < 4; ++it) {
            int idx = tid + it*256;
            int r = idx >> 4, c8 = idx & 15;
            uint4 v = *(const uint4*)&QKV[(size_t)(jt*64 + r)*6144 + 5120 + g*128 + c8*8];
            *(uint4*)&Kv[r][c8*8] = v;
        }
        __syncthreads();
        #pragma unroll
        for (int ks = 0; ks < 2; ++ks) {
            bf16x8 pa = *(const bf16x8*)&SP[l16][jt*64 + ks*32 + qd*8];
            #pragma unroll
            for (int nt = 0; nt < 2; ++nt) {
                union { u16 u[8]; bf16x8 v; } bu;
                const int dc = wave*32 + nt*16 + l16;
                #pragma unroll
                for (int e = 0; e < 8; ++e) bu.u[e] = Kv[ks*32 + qd*8 + e][dc];
                oacc[nt] = __builtin_amdgcn_mfma_f32_16x16x32_bf16(pa, bu.v, oacc[nt], 0, 0, 0);
            }
        }
    }
    __syncthreads();
    #pragma unroll
    for (int nt = 0; nt < 2; ++nt)
        #pragma unroll
        for (int rg = 0; rg < 4; ++rg) {
            int m = qd*4 + rg;
            float v = oacc[nt][rg] / denom[m];
            attn[(size_t)(r0 + m)*4096 + (h << 7) + wave*32 + nt*16 + l16] = f2bf(v);
        }
}

// ---------------------------------------------------------------- host launch
extern "C" void kernel_launch(void* const* d_in, const int* in_sizes, int n_in,
                              void* d_out, int out_size, void* d_ws, size_t ws_size,
                              hipStream_t stream)
{
    const void* hs = d_in[0];
    const void* cs = d_in[1];
    const void* sn = d_in[2];
    const void* wq = d_in[3];
    const void* wk = d_in[4];
    const void* wv = d_in[5];
    const void* wo = d_in[6];
    (void)in_sizes; (void)n_in; (void)out_size; (void)ws_size;

    unsigned char* W = (unsigned char*)d_ws;
    int*    flag  = (int*)   (W);
    int*    cnt   = (int*)   (W + 256);
    float*  rmax0 = (float*) (W + 4608);
    u16*    qkv   = (u16*)   (W + 139776);        // [1024][6144] bf16
    u16*    attn  = (u16*)   (W + 12722688);      // [1024][4096] bf16
    // converted-input buffers (only touched when inputs are fp32)
    u16*    chs   = (u16*)   (W + 21111296);
    u16*    cwq   = (u16*)   (W + 29499904);
    u16*    cwk   = (u16*)   (W + 63054336);
    u16*    cwv   = (u16*)   (W + 71442944);
    u16*    cwo   = (u16*)   (W + 79831552);

    detect_k<<<1, 64, 0, stream>>>((const u32*)cs, flag);
    convert_k<<<4096, 256, 0, stream>>>(flag, (const float*)hs, (const float*)wq,
                                        (const float*)wk, (const float*)wv, (const float*)wo,
                                        chs, cwq, cwk, cwv, cwo);
    // fused QKV projection: C[1024][6144]
    gemm_bt<<<dim3(48, 8), 256, 0, stream>>>(flag,
        (const u16*)hs, chs,
        (const u16*)wq, cwq, (const u16*)wk, cwk, (const u16*)wv, cwv,
        4096, 1024, qkv, nullptr, 1024, 6144, 4096, 6144);
    rope_k<<<10240, 256, 0, stream>>>(flag, qkv, cs, sn);
    rowmax0_k<<<1024, 256, 0, stream>>>(qkv, rmax0);
    zero_k<<<4, 256, 0, stream>>>(cnt, 1024);
    qk_count<<<2048, 256, 0, stream>>>(qkv, rmax0, cnt);
    select_attn<<<2048, 256, 0, stream>>>(qkv, cnt, attn);
    // output projection
    gemm_bt<<<dim3(32, 8), 256, 0, stream>>>(flag,
        attn, attn,
        (const u16*)wo, cwo, (const u16*)wo, cwo, (const u16*)wo, cwo,
        4096, 4096, (u16*)d_out, (float*)d_out, 1024, 4096, 4096, 4096);
}

// Round 4
// 848.305 us; speedup vs baseline: 1.7819x; 1.7819x over previous
//
#include <hip/hip_runtime.h>
#include <hip/hip_bf16.h>
#include <hip/hip_fp16.h>

typedef unsigned int u32;
typedef unsigned short u16;
typedef __bf16 bf16x8 __attribute__((ext_vector_type(8)));
typedef float floatx4 __attribute__((ext_vector_type(4)));

#define SCALE 0.08838834764831845f
#define FETCH_MAX 204

__device__ __forceinline__ float bf2f(u16 u) {
    union { u32 i; float f; } v; v.i = ((u32)u) << 16; return v.f;
}
__device__ __forceinline__ u16 f2bf(float f) {
    union { float f; u32 i; } v; v.f = f;
    u32 r = v.i + 0x7FFFu + ((v.i >> 16) & 1u);
    return (u16)(r >> 16);
}
__device__ __forceinline__ u16 f2h_bits(float f) {
    __half h = __float2half(f);
    union { __half h; u16 u; } v; v.h = h; return v.u;
}
__device__ __forceinline__ float h_bits2f(u16 u) {
    union { __half h; u16 u; } v; v.u = u; return __half2float(v.h);
}
__device__ __forceinline__ u32 h2key(u16 hb) {     // order-preserving fp16 -> u16 key
    return (u32)(u16)(hb ^ ((hb & 0x8000u) ? 0xFFFFu : 0x8000u));
}

// ---------------------------------------------------------------- detect input dtype
__global__ void detect_k(const u32* cosw, int* flag) {
    if (threadIdx.x == 0 && blockIdx.x == 0)
        *flag = (cosw[0] == 0x3F800000u) ? 1 : 0;   // 1 = inputs are fp32
}

__global__ __launch_bounds__(256) void zero_k(int* p, int n) {
    int i = blockIdx.x * 256 + threadIdx.x;
    if (i < n) p[i] = 0;
}

// ---------------------------------------------------------------- convert (fp32 -> bf16), only when flag==1
__global__ __launch_bounds__(256) void convert_k(
    const int* flagp, const float* hs, const float* wq, const float* wk,
    const float* wv, const float* wo,
    u16* chs, u16* cwq, u16* cwk, u16* cwv, u16* cwo)
{
    if (*flagp == 0) return;
    const long S0 = 4194304/4, S1 = 16777216/4, S2 = 4194304/4, S3 = 4194304/4, S4 = 16777216/4;
    const long total = S0+S1+S2+S3+S4;
    for (long idx = (long)blockIdx.x*256 + threadIdx.x; idx < total; idx += (long)gridDim.x*256) {
        const float* src; u16* dst; long o = idx;
        if (o < S0)            { src = hs; dst = chs; }
        else if ((o -= S0) < S1) { src = wq; dst = cwq; }
        else if ((o -= S1) < S2) { src = wk; dst = cwk; }
        else if ((o -= S2) < S3) { src = wv; dst = cwv; }
        else                   { o -= S3; src = wo; dst = cwo; }
        float4 v = ((const float4*)src)[o];
        u32 lo = (u32)f2bf(v.x) | ((u32)f2bf(v.y) << 16);
        u32 hi = (u32)f2bf(v.z) | ((u32)f2bf(v.w) << 16);
        ((uint2*)dst)[o] = make_uint2(lo, hi);
    }
}

// ---------------------------------------------------------------- GEMM  C[M,N] = A[M,K] * B[N,K]^T
__global__ __launch_bounds__(256) void gemm_bt(
    const int* flagp,
    const u16* A0, const u16* A1,
    const u16* B0a, const u16* B0b,
    const u16* B1a, const u16* B1b,
    const u16* B2a, const u16* B2b,
    int n0, int n1,
    u16* Cb, float* Cf,
    int M, int N, int K, int ldc)
{
    const int flag = *flagp;
    const u16* A  = flag ? A1 : A0;
    const u16* Bq = flag ? B0b : B0a;
    const u16* Bk = flag ? B1b : B1a;
    const u16* Bv = flag ? B2b : B2a;
    __shared__ u16 Al[128][72];   // +8 pad: conflict-free b128 frag reads
    __shared__ u16 Bl[128][72];
    const int tid = threadIdx.x;
    const int wave = tid >> 6, lane = tid & 63;
    const int qd = lane >> 4, l16 = lane & 15;
    const int wm = wave & 1, wn = wave >> 1;
    const int m0 = blockIdx.y * 128, nb = blockIdx.x * 128;
    floatx4 acc[4][4];
    floatx4 zf = {0.f, 0.f, 0.f, 0.f};
    for (int mt = 0; mt < 4; ++mt) for (int nt = 0; nt < 4; ++nt) acc[mt][nt] = zf;

    for (int k0 = 0; k0 < K; k0 += 64) {
        #pragma unroll
        for (int it = 0; it < 4; ++it) {
            int idx = tid + it*256;
            int r = idx >> 3, c8 = idx & 7;
            uint4 va = *(const uint4*)&A[(size_t)(m0 + r)*K + k0 + c8*8];
            *(uint4*)&Al[r][c8*8] = va;
            int f = nb + r;
            const u16* Brow = (f < n0) ? (Bq + (size_t)f*K)
                             : (f < n0 + n1) ? (Bk + (size_t)(f - n0)*K)
                             : (Bv + (size_t)(f - n0 - n1)*K);
            uint4 vb = *(const uint4*)&Brow[k0 + c8*8];
            *(uint4*)&Bl[r][c8*8] = vb;
        }
        __syncthreads();
        #pragma unroll
        for (int ks = 0; ks < 2; ++ks) {
            bf16x8 af[4], bfr[4];
            #pragma unroll
            for (int mt = 0; mt < 4; ++mt)
                af[mt] = *(const bf16x8*)&Al[wm*64 + mt*16 + l16][ks*32 + qd*8];
            #pragma unroll
            for (int nt = 0; nt < 4; ++nt)
                bfr[nt] = *(const bf16x8*)&Bl[wn*64 + nt*16 + l16][ks*32 + qd*8];
            #pragma unroll
            for (int mt = 0; mt < 4; ++mt)
                #pragma unroll
                for (int nt = 0; nt < 4; ++nt)
                    acc[mt][nt] = __builtin_amdgcn_mfma_f32_16x16x32_bf16(af[mt], bfr[nt], acc[mt][nt], 0, 0, 0);
        }
        __syncthreads();
    }
    const bool of32 = (Cf != nullptr) && flag;
    #pragma unroll
    for (int mt = 0; mt < 4; ++mt)
        #pragma unroll
        for (int nt = 0; nt < 4; ++nt)
            #pragma unroll
            for (int rg = 0; rg < 4; ++rg) {
                int row = m0 + wm*64 + mt*16 + qd*4 + rg;   // C: row=(lane>>4)*4+reg
                int col = nb + wn*64 + nt*16 + l16;         //    col=lane&15
                float v = acc[mt][nt][rg];
                if (of32) Cf[(size_t)row*ldc + col] = v;
                else      Cb[(size_t)row*ldc + col] = f2bf(v);
            }
}

// ---------------------------------------------------------------- RoPE in-place on Q (slots 0..31) and K (32..39)
__global__ __launch_bounds__(256) void rope_k(const int* flagp, u16* QKV,
                                              const void* cosp, const void* sinp)
{
    const int flag = *flagp;
    long idx = (long)blockIdx.x*256 + threadIdx.x;   // 1024*40*64
    int d = (int)(idx & 63);
    int t = (int)(idx >> 6);
    int slot = t % 40, i = t / 40;
    int col0 = (slot < 32) ? slot*128 : 4096 + (slot - 32)*128;
    size_t base = (size_t)i*6144 + col0;
    float q1 = bf2f(QKV[base + d]), q2 = bf2f(QKV[base + d + 64]);
    float c, s;
    if (flag) { c = ((const float*)cosp)[i*128 + d]; s = ((const float*)sinp)[i*128 + d]; }
    else      { c = bf2f(((const u16*)cosp)[i*128 + d]); s = bf2f(((const u16*)sinp)[i*128 + d]); }
    QKV[base + d]      = f2bf(q1*c - q2*s);
    QKV[base + d + 64] = f2bf(q2*c + q1*s);
}

// ---------------------------------------------------------------- head-0 causal row max (scaled)
__global__ __launch_bounds__(256) void rowmax0_k(const u16* QKV, float* rowmax0)
{
    const int i = blockIdx.x;
    __shared__ float Qs[128];
    __shared__ float wm4[4];
    const int tid = threadIdx.x, wave = tid >> 6, lane = tid & 63;
    if (tid < 16) {
        uint4 v = *(const uint4*)&QKV[(size_t)i*6144 + tid*8];
        Qs[tid*8+0] = bf2f((u16)(v.x & 0xffff)); Qs[tid*8+1] = bf2f((u16)(v.x >> 16));
        Qs[tid*8+2] = bf2f((u16)(v.y & 0xffff)); Qs[tid*8+3] = bf2f((u16)(v.y >> 16));
        Qs[tid*8+4] = bf2f((u16)(v.z & 0xffff)); Qs[tid*8+5] = bf2f((u16)(v.z >> 16));
        Qs[tid*8+6] = bf2f((u16)(v.w & 0xffff)); Qs[tid*8+7] = bf2f((u16)(v.w >> 16));
    }
    __syncthreads();
    float mx = -3.0e38f;
    for (int j = tid; j <= i; j += 256) {
        const u16* Kr = &QKV[(size_t)j*6144 + 4096];   // kv head 0
        float acc = 0.f;
        #pragma unroll
        for (int c8 = 0; c8 < 16; ++c8) {
            uint4 v = *(const uint4*)&Kr[c8*8];
            acc += Qs[c8*8+0]*bf2f((u16)(v.x & 0xffff)) + Qs[c8*8+1]*bf2f((u16)(v.x >> 16));
            acc += Qs[c8*8+2]*bf2f((u16)(v.y & 0xffff)) + Qs[c8*8+3]*bf2f((u16)(v.y >> 16));
            acc += Qs[c8*8+4]*bf2f((u16)(v.z & 0xffff)) + Qs[c8*8+5]*bf2f((u16)(v.z >> 16));
            acc += Qs[c8*8+6]*bf2f((u16)(v.w & 0xffff)) + Qs[c8*8+7]*bf2f((u16)(v.w >> 16));
        }
        mx = fmaxf(mx, acc * SCALE);
    }
    #pragma unroll
    for (int off = 1; off < 64; off <<= 1) mx = fmaxf(mx, __shfl_xor(mx, off, 64));
    if (lane == 0) wm4[wave] = mx;
    __syncthreads();
    if (tid == 0) rowmax0[i] = fmaxf(fmaxf(wm4[0], wm4[1]), fmaxf(wm4[2], wm4[3]));
}

// ---------------------------------------------------------------- per-(head,row) count of s >= head0max - 5
__global__ __launch_bounds__(256) void qk_count(
    const u16* QKV, const float* rowmax0, int* count_sum)
{
    const int bid = blockIdx.x;
    const int h = bid >> 6, rb = bid & 63;
    const int r0 = rb * 16, g = h >> 2;
    __shared__ u16 Kl[128][72];
    __shared__ u16 Ql[16][136];
    __shared__ int redcnt[4][16];
    const int tid = threadIdx.x, wave = tid >> 6, lane = tid & 63;
    const int qd = lane >> 4, l16 = lane & 15;
    {
        int r = tid >> 4, c8 = tid & 15;
        uint4 v = *(const uint4*)&QKV[(size_t)(r0 + r)*6144 + h*128 + c8*8];
        *(uint4*)&Ql[r][c8*8] = v;
    }
    __syncthreads();
    bf16x8 af[4];
    #pragma unroll
    for (int ks = 0; ks < 4; ++ks) af[ks] = *(const bf16x8*)&Ql[l16][ks*32 + qd*8];
    float rm0[4]; int runcnt[4];
    #pragma unroll
    for (int rg = 0; rg < 4; ++rg) {
        runcnt[rg] = 0;
        rm0[rg] = rowmax0[r0 + qd*4 + rg] - 5.0f;
    }
    const int jtiles = (r0 + 16 + 127) >> 7;
    for (int ct = 0; ct < jtiles; ++ct) {
        __syncthreads();
        #pragma unroll
        for (int it = 0; it < 8; ++it) {
            int idx = tid + it*256;
            int r = idx >> 4, c8 = idx & 15;
            uint4 v = *(const uint4*)&QKV[(size_t)(ct*128 + r)*6144 + 4096 + g*128 + c8*8];
            *(uint4*)&Kl[r][c8*8] = v;
        }
        __syncthreads();
        const int jw = wave * 32;
        #pragma unroll
        for (int nt = 0; nt < 2; ++nt) {
            floatx4 sa = {0.f, 0.f, 0.f, 0.f};
            #pragma unroll
            for (int ks = 0; ks < 4; ++ks) {
                bf16x8 bfr = *(const bf16x8*)&Kl[jw + nt*16 + l16][ks*32 + qd*8];
                sa = __builtin_amdgcn_mfma_f32_16x16x32_bf16(af[ks], bfr, sa, 0, 0, 0);
            }
            const int jc = ct*128 + jw + nt*16 + l16;
            #pragma unroll
            for (int rg = 0; rg < 4; ++rg) {
                float s = sa[rg] * SCALE;
                int i = r0 + qd*4 + rg;
                if (jc <= i) runcnt[rg] += (s >= rm0[rg]) ? 1 : 0;
            }
        }
    }
    #pragma unroll
    for (int off = 1; off < 16; off <<= 1)
        #pragma unroll
        for (int rg = 0; rg < 4; ++rg)
            runcnt[rg] += __shfl_xor(runcnt[rg], off, 64);
    if (l16 == 0)
        for (int rg = 0; rg < 4; ++rg)
            redcnt[wave][qd*4 + rg] = runcnt[rg];
    __syncthreads();
    if (tid < 16) {
        int c = redcnt[0][tid] + redcnt[1][tid] + redcnt[2][tid] + redcnt[3][tid];
        atomicAdd(&count_sum[r0 + tid], c);
    }
}

// ---------------------------------------------------------------- fused: scores (MFMA->LDS fp16) -> LDS-key top-k -> softmax -> PV
// No global score tensor: everything stays in LDS (ws footprint stays at the R2-verified 21 MB).
// Phase B uses NO per-thread arrays (the R2 version's sv[16]/key[16] spilled to scratch ->
// 256 dependent scratch loads per bisection -> the 1129us serialization).
__global__ __launch_bounds__(256) void select_attn(
    const u16* QKV, const int* count_sum, u16* attn)
{
    const int bid = blockIdx.x;
    const int h = bid >> 6, rb = bid & 63;
    const int r0 = rb * 16, g = h >> 2;
    const int tid = threadIdx.x, wave = tid >> 6, lane = tid & 63;
    const int qd = lane >> 4, l16 = lane & 15;
    __shared__ u16 Ql[16][136];
    __shared__ u16 Kv[64][136];      // K tile in phase A, V tile in phase C
    __shared__ u16 SP[16][1032];     // fp16 scores, overwritten in-place with bf16 probs
    __shared__ float denom[16];

    const int jtc = (r0 + 16 + 63) >> 6;   // number of 64-wide j tiles

    // stage Q (16 x 128)
    {
        int r = tid >> 4, c8 = tid & 15;
        uint4 v = *(const uint4*)&QKV[(size_t)(r0 + r)*6144 + h*128 + c8*8];
        *(uint4*)&Ql[r][c8*8] = v;
    }
    __syncthreads();
    bf16x8 af[4];
    #pragma unroll
    for (int ks = 0; ks < 4; ++ks) af[ks] = *(const bf16x8*)&Ql[l16][ks*32 + qd*8];

    // ---- phase A: scores (MFMA) -> SP as fp16   [verbatim from the R2-passing kernel]
    for (int ct = 0; ct < jtc; ++ct) {
        __syncthreads();
        #pragma unroll
        for (int it = 0; it < 4; ++it) {
            int idx = tid + it*256;
            int r = idx >> 4, c8 = idx & 15;
            uint4 v = *(const uint4*)&QKV[(size_t)(ct*64 + r)*6144 + 4096 + g*128 + c8*8];
            *(uint4*)&Kv[r][c8*8] = v;
        }
        __syncthreads();
        floatx4 sa = {0.f, 0.f, 0.f, 0.f};
        #pragma unroll
        for (int ks = 0; ks < 4; ++ks) {
            bf16x8 bfr = *(const bf16x8*)&Kv[wave*16 + l16][ks*32 + qd*8];
            sa = __builtin_amdgcn_mfma_f32_16x16x32_bf16(af[ks], bfr, sa, 0, 0, 0);
        }
        #pragma unroll
        for (int rg = 0; rg < 4; ++rg)
            SP[qd*4 + rg][ct*64 + wave*16 + l16] = f2h_bits(sa[rg] * SCALE);
    }
    __syncthreads();

    // ---- phase B: per wave-row exact top-k (bisection over LDS keys, no register arrays) + probs
    for (int batch = 0; batch < 4; ++batch) {
        const int m = batch*4 + wave;      // rows are wave-exclusive: no cross-wave SP hazard
        const int i = r0 + m, n = i + 1;
        const int nch = (n + 63) >> 6;
        const bool full = (i < FETCH_MAX);

        float rmax = -3.0e38f;
        for (int c = 0; c < nch; ++c) {
            int j = c*64 + lane;
            if (j < n) rmax = fmaxf(rmax, h_bits2f(SP[m][j]));
        }
        #pragma unroll
        for (int off = 1; off < 64; off <<= 1) rmax = fmaxf(rmax, __shfl_xor(rmax, off, 64));

        u32 Kstar = 0; int quota = 0;
        if (!full) {
            int k = count_sum[i] >> 5;              // floor(mean over 32 heads)
            if (k > FETCH_MAX) k = FETCH_MAX;
            if (k < 1) k = 1;
            // bisection: Kstar = max t with count(key >= t) >= k; keys recomputed from LDS each round
            u32 t = 0;
            for (int bit = 15; bit >= 0; --bit) {
                u32 tc = t | (1u << bit);
                int cnt = 0;
                for (int c = 0; c < nch; ++c) {
                    int j = c*64 + lane;
                    u32 key = h2key(SP[m][j]);
                    cnt += __popcll(__ballot(j < n && key >= tc));
                }
                if (cnt >= k) t = tc;
            }
            Kstar = t;
            int cntgt = 0;
            for (int c = 0; c < nch; ++c) {
                int j = c*64 + lane;
                u32 key = h2key(SP[m][j]);
                cntgt += __popcll(__ballot(j < n && key > Kstar));
            }
            quota = k - cntgt;                      // kept among keys == Kstar (>=1)
        }
        // probs (unnormalized); ties at Kstar kept by ascending index (stable argsort)
        float psum = 0.f; int eqbase = 0;
        for (int c = 0; c < nch; ++c) {
            int j = c*64 + lane;
            u16 hb = SP[m][j];
            u32 key = h2key(hb);
            bool valid = (j < n);
            bool keep;
            if (full) keep = valid;
            else {
                bool eq = valid && (key == Kstar);
                unsigned long long em = __ballot(eq);
                int rk = eqbase + __popcll(em & ((1ull << lane) - 1ull));
                keep = valid && ((key > Kstar) || (eq && rk < quota));
                eqbase += __popcll(em);
            }
            float p = keep ? __expf(h_bits2f(hb) - rmax) : 0.f;
            psum += p;
            SP[m][j] = f2bf(p);                     // read-then-write same j: safe in-iteration
        }
        for (int c = nch; c < jtc; ++c) SP[m][c*64 + lane] = 0;
        #pragma unroll
        for (int off = 1; off < 64; off <<= 1) psum += __shfl_xor(psum, off, 64);
        if (lane == 0) denom[m] = psum;
    }
    __syncthreads();

    // ---- phase C: PV over all tiles   [verbatim from the R2-passing kernel]
    floatx4 oacc[2];
    floatx4 zf = {0.f, 0.f, 0.f, 0.f};
    oacc[0] = zf; oacc[1] = zf;
    for (int jt = 0; jt < jtc; ++jt) {
        __syncthreads();
        #pragma unroll
        for (int it = 0; it < 4; ++it) {
            int idx = tid + it*256;
            int r = idx >> 4, c8 = idx & 15;
            uint4 v = *(const uint4*)&QKV[(size_t)(jt*64 + r)*6144 + 5120 + g*128 + c8*8];
            *(uint4*)&Kv[r][c8*8] = v;
        }
        __syncthreads();
        #pragma unroll
        for (int ks = 0; ks < 2; ++ks) {
            bf16x8 pa = *(const bf16x8*)&SP[l16][jt*64 + ks*32 + qd*8];
            #pragma unroll
            for (int nt = 0; nt < 2; ++nt) {
                union { u16 u[8]; bf16x8 v; } bu;
                const int dc = wave*32 + nt*16 + l16;
                #pragma unroll
                for (int e = 0; e < 8; ++e) bu.u[e] = Kv[ks*32 + qd*8 + e][dc];
                oacc[nt] = __builtin_amdgcn_mfma_f32_16x16x32_bf16(pa, bu.v, oacc[nt], 0, 0, 0);
            }
        }
    }
    __syncthreads();
    #pragma unroll
    for (int nt = 0; nt < 2; ++nt)
        #pragma unroll
        for (int rg = 0; rg < 4; ++rg) {
            int m = qd*4 + rg;
            float v = oacc[nt][rg] / denom[m];
            attn[(size_t)(r0 + m)*4096 + (h << 7) + wave*32 + nt*16 + l16] = f2bf(v);
        }
}

// ---------------------------------------------------------------- host launch
extern "C" void kernel_launch(void* const* d_in, const int* in_sizes, int n_in,
                              void* d_out, int out_size, void* d_ws, size_t ws_size,
                              hipStream_t stream)
{
    const void* hs = d_in[0];
    const void* cs = d_in[1];
    const void* sn = d_in[2];
    const void* wq = d_in[3];
    const void* wk = d_in[4];
    const void* wv = d_in[5];
    const void* wo = d_in[6];
    (void)in_sizes; (void)n_in; (void)out_size; (void)ws_size;

    unsigned char* W = (unsigned char*)d_ws;
    int*    flag  = (int*)   (W);
    int*    cnt   = (int*)   (W + 256);
    float*  rmax0 = (float*) (W + 4608);
    u16*    qkv   = (u16*)   (W + 139776);        // [1024][6144] bf16
    u16*    attn  = (u16*)   (W + 12722688);      // [1024][4096] bf16
    // converted-input buffers (only touched when inputs are fp32; flag=0 path never writes them)
    u16*    chs   = (u16*)   (W + 21111296);
    u16*    cwq   = (u16*)   (W + 29499904);
    u16*    cwk   = (u16*)   (W + 63054336);
    u16*    cwv   = (u16*)   (W + 71442944);
    u16*    cwo   = (u16*)   (W + 79831552);

    detect_k<<<1, 64, 0, stream>>>((const u32*)cs, flag);
    convert_k<<<4096, 256, 0, stream>>>(flag, (const float*)hs, (const float*)wq,
                                        (const float*)wk, (const float*)wv, (const float*)wo,
                                        chs, cwq, cwk, cwv, cwo);
    // fused QKV projection: C[1024][6144]
    gemm_bt<<<dim3(48, 8), 256, 0, stream>>>(flag,
        (const u16*)hs, chs,
        (const u16*)wq, cwq, (const u16*)wk, cwk, (const u16*)wv, cwv,
        4096, 1024, qkv, nullptr, 1024, 6144, 4096, 6144);
    rope_k<<<10240, 256, 0, stream>>>(flag, qkv, cs, sn);
    rowmax0_k<<<1024, 256, 0, stream>>>(qkv, rmax0);
    zero_k<<<4, 256, 0, stream>>>(cnt, 1024);
    qk_count<<<2048, 256, 0, stream>>>(qkv, rmax0, cnt);
    select_attn<<<2048, 256, 0, stream>>>(qkv, cnt, attn);
    // output projection
    gemm_bt<<<dim3(32, 8), 256, 0, stream>>>(flag,
        attn, attn,
        (const u16*)wo, cwo, (const u16*)wo, cwo, (const u16*)wo, cwo,
        4096, 4096, (u16*)d_out, (float*)d_out, 1024, 4096, 4096, 4096);
}